// Round 2
// baseline (826.430 us; speedup 1.0000x reference)
//
#include <hip/hip_runtime.h>
#include <hip/hip_bf16.h>

typedef __attribute__((ext_vector_type(8))) __bf16 bf16x8;
typedef __attribute__((ext_vector_type(8))) short s16x8;
typedef __attribute__((ext_vector_type(4))) float f32x4;

#define DEVI __device__ __forceinline__

DEVI f32x4 mfma16(bf16x8 a, bf16x8 b, f32x4 c) {
  return __builtin_amdgcn_mfma_f32_16x16x32_bf16((s16x8)a, (s16x8)b, c, 0, 0, 0);
}

constexpr float SCALE = 0.08838834764831845f;  // (4096/32)^-0.5 = 1/sqrt(128)

// ---------------- workspace layout (bytes), peak ~140 MB ----------------
// Region [0, 64MB) is time-shared: {wqT, wkpT, wkmT, lnq} until the QK GEMMs
// finish, then {wvpT, wvmT} (stream-ordered, no overlap in lifetime).
constexpr size_t MB = 1024ull * 1024ull;
constexpr size_t OFF_WQT  = 0;         // [1024][8192] bf16 = 16MB
constexpr size_t OFF_WKPT = 16 * MB;   // [1024][4096] bf16 = 8MB
constexpr size_t OFF_WKMT = 24 * MB;   // [1024][4096] bf16 = 8MB
constexpr size_t OFF_LNQ  = 32 * MB;   // [2048][8192] bf16 = 32MB
constexpr size_t OFF_WVPT = 0;         // [4096][4096] bf16 = 32MB (aliases wqT+wkpT+wkmT)
constexpr size_t OFF_WVMT = 32 * MB;   // [4096][4096] bf16 = 32MB (aliases lnq)
constexpr size_t OFF_LNP  = 64 * MB;   // [2048][4096] bf16 = 16MB
constexpr size_t OFF_LNM  = 80 * MB;   // [2048][4096] bf16 = 16MB
constexpr size_t OFF_Q    = 96 * MB;   // [2048][1024] bf16 = 4MB
constexpr size_t OFF_KP   = 100 * MB;  // [2048][1024] bf16 = 4MB
constexpr size_t OFF_KM   = 104 * MB;  // [2048][1024] bf16 = 4MB
constexpr size_t OFF_VPT  = 108 * MB;  // [4096][2048] bf16 = 16MB (V^T)
constexpr size_t OFF_VMT  = 124 * MB;  // [4096][2048] bf16 = 16MB (V^T)
constexpr size_t OFF_BQ   = 140 * MB;  // [1024] f32
constexpr size_t OFF_BKP  = OFF_BQ  + 1024 * 4;
constexpr size_t OFF_BKM  = OFF_BKP + 1024 * 4;
constexpr size_t OFF_BVP  = OFF_BKM + 1024 * 4;
constexpr size_t OFF_BVM  = OFF_BVP + 4096 * 4;
constexpr int    N_BIAS_F = 3 * 1024 + 2 * 4096;  // 11264 floats

// async global->LDS, 16B per lane. LDS dest is wave-uniform base; HW adds lane*16.
DEVI void async16(void* lds, const void* g) {
  __builtin_amdgcn_global_load_lds(
      (const __attribute__((address_space(1))) void*)g,
      (__attribute__((address_space(3))) void*)lds, 16, 0, 0);
}

// ---------------- zero bias accumulators ----------------
__global__ void zero_kernel(float* p, int n) {
  int i = blockIdx.x * 256 + threadIdx.x;
  if (i < n) p[i] = 0.f;
}

// -------- weight convert: W[K][N] f32 -> Wt[N][K] bf16 (gamma-folded), bias += beta@W ---
__global__ __launch_bounds__(256) void wconv_kernel(
    const float* __restrict__ W, const float* __restrict__ gam,
    const float* __restrict__ bet, __bf16* __restrict__ wT,
    float* __restrict__ biasOut, int K, int N) {
  __shared__ float tile[64][65];
  const int n0 = blockIdx.x * 64, k0 = blockIdx.y * 64;
  const int t = threadIdx.x;
  const int nl = t & 63, kb = t >> 6;
  float pb = 0.f;
#pragma unroll
  for (int i = 0; i < 16; ++i) {
    const int kl = kb * 16 + i;
    const int k = k0 + kl;
    const float w = W[(long)k * N + n0 + nl];  // coalesced 256B/64 lanes
    tile[kl][nl] = w * gam[k];
    pb += bet[k] * w;
  }
  atomicAdd(biasOut + n0 + nl, pb);
  __syncthreads();
  const int klw = t & 63;
#pragma unroll
  for (int i = 0; i < 16; ++i) {
    const int nloc = kb * 16 + i;
    wT[(long)(n0 + nloc) * K + k0 + klw] = (__bf16)tile[klw][nloc];  // coalesced 128B
  }
}

// ---- unfold + 3 LayerNorms (x-hat only; affine folded into weights) -------------------
// block = one (b, patch n). thread t owns features f = t*16 .. t*16+15
// (c = t>>2, ki = (t&3)*2 + j/8, kj = j&7). u_q stats = sum of pan/ms partial sums.
__global__ __launch_bounds__(256) void ln_kernel(
    const float* __restrict__ pan, const float* __restrict__ ms,
    __bf16* __restrict__ lnq, __bf16* __restrict__ lnp, __bf16* __restrict__ lnm) {
  const int bid = blockIdx.x;
  const int b = bid >> 10, n = bid & 1023;
  const int ph = n >> 5, pw = n & 31;
  const int t = threadIdx.x;
  const int c = t >> 2, kp2 = t & 3;

  const long base = ((long)(b * 64 + c) << 16) + (long)(ph * 8) * 256 + pw * 8;
  float rp[16], rm[16];
#pragma unroll
  for (int kk = 0; kk < 2; ++kk) {
    const int ki = kp2 * 2 + kk;
    const f32x4* p0 = (const f32x4*)(pan + base + ki * 256);
    const f32x4* m0 = (const f32x4*)(ms + base + ki * 256);
    f32x4 pa = p0[0], pb = p0[1], ma = m0[0], mb = m0[1];
#pragma unroll
    for (int j = 0; j < 4; ++j) {
      rp[kk * 8 + j] = pa[j];
      rp[kk * 8 + 4 + j] = pb[j];
      rm[kk * 8 + j] = ma[j];
      rm[kk * 8 + 4 + j] = mb[j];
    }
  }
  float sp = 0, sp2 = 0, smm = 0, sm2 = 0;
#pragma unroll
  for (int j = 0; j < 16; ++j) {
    sp += rp[j]; sp2 += rp[j] * rp[j];
    smm += rm[j]; sm2 += rm[j] * rm[j];
  }
#pragma unroll
  for (int msk = 1; msk < 64; msk <<= 1) {
    sp += __shfl_xor(sp, msk);
    sp2 += __shfl_xor(sp2, msk);
    smm += __shfl_xor(smm, msk);
    sm2 += __shfl_xor(sm2, msk);
  }
  __shared__ float red[4][4];
  const int wid = t >> 6;
  if ((t & 63) == 0) { red[wid][0] = sp; red[wid][1] = sp2; red[wid][2] = smm; red[wid][3] = sm2; }
  __syncthreads();
  sp = red[0][0] + red[1][0] + red[2][0] + red[3][0];
  sp2 = red[0][1] + red[1][1] + red[2][1] + red[3][1];
  smm = red[0][2] + red[1][2] + red[2][2] + red[3][2];
  sm2 = red[0][3] + red[1][3] + red[2][3] + red[3][3];

  const float mu_p = sp * (1.f / 4096.f);
  const float rs_p = rsqrtf(sp2 * (1.f / 4096.f) - mu_p * mu_p + 1e-5f);
  const float mu_m = smm * (1.f / 4096.f);
  const float rs_m = rsqrtf(sm2 * (1.f / 4096.f) - mu_m * mu_m + 1e-5f);
  const float mu_q = (sp + smm) * (1.f / 8192.f);
  const float rs_q = rsqrtf((sp2 + sm2) * (1.f / 8192.f) - mu_q * mu_q + 1e-5f);

  const long row = bid;  // b*1024 + n
  const int f0 = t * 16;
  bf16x8 v0, v1;
#pragma unroll
  for (int j = 0; j < 8; ++j) { v0[j] = (__bf16)((rp[j] - mu_p) * rs_p); v1[j] = (__bf16)((rp[8 + j] - mu_p) * rs_p); }
  *(bf16x8*)(lnp + row * 4096 + f0) = v0;
  *(bf16x8*)(lnp + row * 4096 + f0 + 8) = v1;
#pragma unroll
  for (int j = 0; j < 8; ++j) { v0[j] = (__bf16)((rm[j] - mu_m) * rs_m); v1[j] = (__bf16)((rm[8 + j] - mu_m) * rs_m); }
  *(bf16x8*)(lnm + row * 4096 + f0) = v0;
  *(bf16x8*)(lnm + row * 4096 + f0 + 8) = v1;
#pragma unroll
  for (int j = 0; j < 8; ++j) { v0[j] = (__bf16)((rp[j] - mu_q) * rs_q); v1[j] = (__bf16)((rp[8 + j] - mu_q) * rs_q); }
  *(bf16x8*)(lnq + row * 8192 + f0) = v0;
  *(bf16x8*)(lnq + row * 8192 + f0 + 8) = v1;
#pragma unroll
  for (int j = 0; j < 8; ++j) { v0[j] = (__bf16)((rm[j] - mu_q) * rs_q); v1[j] = (__bf16)((rm[8 + j] - mu_q) * rs_q); }
  *(bf16x8*)(lnq + row * 8192 + 4096 + f0) = v0;
  *(bf16x8*)(lnq + row * 8192 + 4096 + f0 + 8) = v1;
}

// ---- batched GEMM: out[m1][m2] = X[m1][:] . Y[m2][:] (both [rows][K] bf16) ------------
// m97 structure: 128x128 tile, BK=32, global_load_lds w16, 16x mfma 16x16x32 per K-step.
// blockIdx.z selects the operand set (ternary select: no dynamic kernarg indexing).
struct G3 {
  const __bf16 *X0, *X1, *X2, *Y0, *Y1, *Y2;
  __bf16 *O0, *O1, *O2;
  const float *bX0, *bX1, *bX2, *bY0, *bY1, *bY2;
  int K0, K1, K2, M2;
};

__global__ __launch_bounds__(256, 2) void gemm_batch(G3 g) {
  const int z = blockIdx.z;
  const __bf16* X = z == 0 ? g.X0 : (z == 1 ? g.X1 : g.X2);
  const __bf16* Y = z == 0 ? g.Y0 : (z == 1 ? g.Y1 : g.Y2);
  __bf16* out = z == 0 ? g.O0 : (z == 1 ? g.O1 : g.O2);
  const float* biasX = z == 0 ? g.bX0 : (z == 1 ? g.bX1 : g.bX2);
  const float* biasY = z == 0 ? g.bY0 : (z == 1 ? g.bY1 : g.bY2);
  const int K = z == 0 ? g.K0 : (z == 1 ? g.K1 : g.K2);
  const int M2 = g.M2;

  __shared__ __bf16 xt[128 * 32];
  __shared__ __bf16 yt[128 * 32];
  const int t = threadIdx.x;
  const int lane = t & 63, wid = t >> 6;
  const int wr = wid >> 1, wc = wid & 1;
  const int l15 = lane & 15, l4 = lane >> 4;
  const long x0 = (long)blockIdx.x * 128;
  const long y0 = (long)blockIdx.y * 128;

  f32x4 acc[4][4] = {};

  for (int kk = 0; kk < K; kk += 32) {
    __syncthreads();
#pragma unroll
    for (int i = 0; i < 2; ++i) {
      const int chunk = i * 256 + t;  // 512 chunks of 16B per 8KB tile
      const int r = chunk >> 2, q = chunk & 3;
      async16((char*)xt + (i * 256 + wid * 64) * 16, X + (x0 + r) * K + kk + q * 8);
      async16((char*)yt + (i * 256 + wid * 64) * 16, Y + (y0 + r) * K + kk + q * 8);
    }
    __syncthreads();
    bf16x8 a[4], bb[4];
#pragma unroll
    for (int mi = 0; mi < 4; ++mi)
      a[mi] = *(const bf16x8*)(xt + (wr * 64 + mi * 16 + l15) * 32 + l4 * 8);
#pragma unroll
    for (int ni = 0; ni < 4; ++ni)
      bb[ni] = *(const bf16x8*)(yt + (wc * 64 + ni * 16 + l15) * 32 + l4 * 8);
#pragma unroll
    for (int mi = 0; mi < 4; ++mi)
#pragma unroll
      for (int ni = 0; ni < 4; ++ni)
        acc[mi][ni] = mfma16(a[mi], bb[ni], acc[mi][ni]);
  }

#pragma unroll
  for (int mi = 0; mi < 4; ++mi) {
#pragma unroll
    for (int r = 0; r < 4; ++r) {
      const long row = x0 + wr * 64 + mi * 16 + l4 * 4 + r;
      const float bx = biasX ? biasX[row] : 0.f;
#pragma unroll
      for (int ni = 0; ni < 4; ++ni) {
        const long col = y0 + wc * 64 + ni * 16 + l15;
        const float by = biasY ? biasY[col] : 0.f;
        out[row * M2 + col] = (__bf16)(acc[mi][ni][r] + bx + by);
      }
    }
  }
}

// ---------------- fused flash attention + fold + residual ------------------------------
// grid 1024: bid = b*512 + tt*256 + g*8 + qt. 4 waves x 32 q-rows = 128-row q-tile.
__global__ __launch_bounds__(256, 2) void attn_kernel(
    const __bf16* __restrict__ Qm, const __bf16* __restrict__ Kpm,
    const __bf16* __restrict__ Kmm, const __bf16* __restrict__ VpT,
    const __bf16* __restrict__ VmT, const float* __restrict__ pan,
    const float* __restrict__ ms, float* __restrict__ out) {
  __shared__ __bf16 ktile[128 * 32];     // [key][c], chunk-swizzled
  __shared__ __bf16 vtile[128 * 128];    // [d][key], chunk-swizzled (from V^T)
  __shared__ __bf16 ptile[4][32 * 128];  // per-wave P [q][key], chunk-swizzled

  const int bid = blockIdx.x;
  const int qt = bid & 7, g = (bid >> 3) & 31, tt = (bid >> 8) & 1, b = bid >> 9;
  const __bf16* Kmat = tt ? Kmm : Kpm;
  const __bf16* VT = tt ? VmT : VpT;
  const float* res = tt ? ms : pan;

  const int t = threadIdx.x, lane = t & 63, wid = t >> 6;
  const int l15 = lane & 15, l4 = lane >> 4;

  // Q A-frags straight from global (row = l15, k = l4*8+j)
  bf16x8 qf[2];
#pragma unroll
  for (int mi = 0; mi < 2; ++mi) {
    const long row = (long)b * 1024 + qt * 128 + wid * 32 + mi * 16 + l15;
    qf[mi] = *(const bf16x8*)(Qm + row * 1024 + g * 32 + l4 * 8);
  }

  f32x4 acc[2][8] = {};
  float mrun[2][4], lrun[2][4];
#pragma unroll
  for (int mi = 0; mi < 2; ++mi)
#pragma unroll
    for (int r = 0; r < 4; ++r) { mrun[mi][r] = -1e30f; lrun[mi][r] = 0.f; }

  for (int kt = 0; kt < 8; ++kt) {
    __syncthreads();  // prev iter done reading ktile/vtile
    // stage K tile: 512 chunks; swizzle: slot = q ^ ((key>>1)&3)  (8-way -> 2-way)
#pragma unroll
    for (int i = 0; i < 2; ++i) {
      const int chunk = i * 256 + t;
      const int key = chunk >> 2, slot = chunk & 3;
      const int q = slot ^ ((key >> 1) & 3);
      async16((char*)ktile + (i * 256 + wid * 64) * 16,
              Kmat + (long)(b * 1024 + kt * 128 + key) * 1024 + g * 32 + q * 8);
    }
    // stage V^T tile: 2048 chunks; swizzle: slot = c16 ^ (d&15)  (16-way -> 2-way)
#pragma unroll
    for (int i = 0; i < 8; ++i) {
      const int chunk = i * 256 + t;
      const int d = chunk >> 4, slot = chunk & 15;
      const int c16 = slot ^ (d & 15);
      async16((char*)vtile + (i * 256 + wid * 64) * 16,
              VT + (long)(g * 128 + d) * 2048 + b * 1024 + kt * 128 + c16 * 8);
    }
    __syncthreads();

    // S = Q K^T (contraction = 32 = one MFMA per 16-key block)
    f32x4 s[2][8];
#pragma unroll
    for (int ni = 0; ni < 8; ++ni) {
      const int key = ni * 16 + l15;
      const int slot = l4 ^ ((key >> 1) & 3);
      const bf16x8 kf = *(const bf16x8*)(ktile + key * 32 + slot * 8);
      f32x4 zz = {0.f, 0.f, 0.f, 0.f};
      s[0][ni] = mfma16(qf[0], kf, zz);
      s[1][ni] = mfma16(qf[1], kf, zz);
    }

    // online softmax (row = l4*4+r; the 16 l15-lanes share a row -> shfl_xor<16 reduce)
#pragma unroll
    for (int mi = 0; mi < 2; ++mi) {
#pragma unroll
      for (int r = 0; r < 4; ++r) {
        float tmax = -1e30f;
#pragma unroll
        for (int ni = 0; ni < 8; ++ni) tmax = fmaxf(tmax, s[mi][ni][r]);
        tmax *= SCALE;
#pragma unroll
        for (int msk = 1; msk < 16; msk <<= 1) tmax = fmaxf(tmax, __shfl_xor(tmax, msk));
        const float mnew = fmaxf(mrun[mi][r], tmax);
        const float alpha = __expf(mrun[mi][r] - mnew);
        mrun[mi][r] = mnew;
        float tsum = 0.f;
#pragma unroll
        for (int ni = 0; ni < 8; ++ni) {
          const float p = __expf(s[mi][ni][r] * SCALE - mnew);
          s[mi][ni][r] = p;
          tsum += p;
        }
#pragma unroll
        for (int msk = 1; msk < 16; msk <<= 1) tsum += __shfl_xor(tsum, msk);
        lrun[mi][r] = lrun[mi][r] * alpha + tsum;
#pragma unroll
        for (int ni = 0; ni < 8; ++ni) acc[mi][ni][r] *= alpha;
      }
    }

    // P -> per-wave LDS bf16 (same swizzle family as vtile)
#pragma unroll
    for (int mi = 0; mi < 2; ++mi)
#pragma unroll
      for (int ni = 0; ni < 8; ++ni)
#pragma unroll
        for (int r = 0; r < 4; ++r) {
          const int q = mi * 16 + l4 * 4 + r;
          const int key = ni * 16 + l15;
          const int off = q * 256 + (((key >> 3) ^ (q & 15)) * 16) + (key & 7) * 2;
          *(__bf16*)((char*)ptile[wid] + off) = (__bf16)s[mi][ni][r];
        }
    __syncthreads();

    // O += P V (A-frag from ptile, B-frag from vtile)
#pragma unroll
    for (int ks = 0; ks < 4; ++ks) {
      bf16x8 pa[2];
#pragma unroll
      for (int mi = 0; mi < 2; ++mi) {
        const int q = mi * 16 + l15;
        const int slot = (ks * 4 + l4) ^ (q & 15);
        pa[mi] = *(const bf16x8*)((char*)ptile[wid] + q * 256 + slot * 16);
      }
#pragma unroll
      for (int ni = 0; ni < 8; ++ni) {
        const int d = ni * 16 + l15;
        const int slot = (ks * 4 + l4) ^ (d & 15);
        const bf16x8 vf = *(const bf16x8*)((char*)vtile + d * 256 + slot * 16);
        acc[0][ni] = mfma16(pa[0], vf, acc[0][ni]);
        acc[1][ni] = mfma16(pa[1], vf, acc[1][ni]);
      }
    }
  }

  // epilogue: 1/l, fold, residual, fp32 store
#pragma unroll
  for (int mi = 0; mi < 2; ++mi) {
#pragma unroll
    for (int r = 0; r < 4; ++r) {
      const float inv = 1.f / lrun[mi][r];
      const int n = qt * 128 + wid * 32 + mi * 16 + l4 * 4 + r;
      const int ph = n >> 5, pw = n & 31;
#pragma unroll
      for (int ni = 0; ni < 8; ++ni) {
        const int d = ni * 16 + l15;
        const int ch = 2 * g + (d >> 6);
        const int pix = (ph * 8 + ((d >> 3) & 7)) * 256 + pw * 8 + (d & 7);
        const long ridx = (long)(b * 64 + ch) * 65536 + pix;
        const long oidx = (long)(b * 128 + tt * 64 + ch) * 65536 + pix;
        out[oidx] = acc[mi][ni][r] * inv + res[ridx];
      }
    }
  }
}

// ---------------- launcher ----------------
extern "C" void kernel_launch(void* const* d_in, const int* in_sizes, int n_in,
                              void* d_out, int out_size, void* d_ws, size_t ws_size,
                              hipStream_t stream) {
  const float* pan = (const float*)d_in[0];
  const float* ms = (const float*)d_in[1];
  const float* g_q = (const float*)d_in[2];
  const float* b_q = (const float*)d_in[3];
  const float* g_kp = (const float*)d_in[4];
  const float* b_kp = (const float*)d_in[5];
  const float* g_vp = (const float*)d_in[6];
  const float* b_vp = (const float*)d_in[7];
  const float* g_km = (const float*)d_in[8];
  const float* b_km = (const float*)d_in[9];
  const float* g_vm = (const float*)d_in[10];
  const float* b_vm = (const float*)d_in[11];
  const float* w_q = (const float*)d_in[12];
  const float* w_kp = (const float*)d_in[13];
  const float* w_vp = (const float*)d_in[14];
  const float* w_km = (const float*)d_in[15];
  const float* w_vm = (const float*)d_in[16];

  char* ws = (char*)d_ws;
  __bf16* wqT = (__bf16*)(ws + OFF_WQT);
  __bf16* wkpT = (__bf16*)(ws + OFF_WKPT);
  __bf16* wkmT = (__bf16*)(ws + OFF_WKMT);
  __bf16* lnq = (__bf16*)(ws + OFF_LNQ);
  __bf16* wvpT = (__bf16*)(ws + OFF_WVPT);
  __bf16* wvmT = (__bf16*)(ws + OFF_WVMT);
  __bf16* lnp = (__bf16*)(ws + OFF_LNP);
  __bf16* lnm = (__bf16*)(ws + OFF_LNM);
  __bf16* Qm = (__bf16*)(ws + OFF_Q);
  __bf16* Kpm = (__bf16*)(ws + OFF_KP);
  __bf16* Kmm = (__bf16*)(ws + OFF_KM);
  __bf16* VpT = (__bf16*)(ws + OFF_VPT);
  __bf16* VmT = (__bf16*)(ws + OFF_VMT);
  float* bq = (float*)(ws + OFF_BQ);
  float* bkp = (float*)(ws + OFF_BKP);
  float* bkm = (float*)(ws + OFF_BKM);
  float* bvp = (float*)(ws + OFF_BVP);
  float* bvm = (float*)(ws + OFF_BVM);

  const dim3 blk(256);

  zero_kernel<<<(N_BIAS_F + 255) / 256, blk, 0, stream>>>(bq, N_BIAS_F);

  // Q/K weights + LN first (lnq and the QK weights share region A with V weights)
  wconv_kernel<<<dim3(16, 128), blk, 0, stream>>>(w_q, g_q, b_q, wqT, bq, 8192, 1024);
  wconv_kernel<<<dim3(16, 64), blk, 0, stream>>>(w_kp, g_kp, b_kp, wkpT, bkp, 4096, 1024);
  wconv_kernel<<<dim3(16, 64), blk, 0, stream>>>(w_km, g_km, b_km, wkmT, bkm, 4096, 1024);

  ln_kernel<<<2048, blk, 0, stream>>>(pan, ms, lnq, lnp, lnm);

  // Q/K projections in one launch (z = 0,1,2): out[m][n]
  {
    G3 g;
    g.X0 = lnq; g.X1 = lnp; g.X2 = lnm;
    g.Y0 = wqT; g.Y1 = wkpT; g.Y2 = wkmT;
    g.O0 = Qm; g.O1 = Kpm; g.O2 = Kmm;
    g.bX0 = nullptr; g.bX1 = nullptr; g.bX2 = nullptr;
    g.bY0 = bq; g.bY1 = bkp; g.bY2 = bkm;
    g.K0 = 8192; g.K1 = 4096; g.K2 = 4096; g.M2 = 1024;
    gemm_batch<<<dim3(16, 8, 3), blk, 0, stream>>>(g);
  }

  // now region A is free: convert V weights into it
  wconv_kernel<<<dim3(64, 64), blk, 0, stream>>>(w_vp, g_vp, b_vp, wvpT, bvp, 4096, 4096);
  wconv_kernel<<<dim3(64, 64), blk, 0, stream>>>(w_vm, g_vm, b_vm, wvmT, bvm, 4096, 4096);

  // V projections in one launch (z = 0,1), operands swapped -> V^T[d][token]
  {
    G3 g;
    g.X0 = wvpT; g.X1 = wvmT; g.X2 = wvmT;
    g.Y0 = lnp; g.Y1 = lnm; g.Y2 = lnm;
    g.O0 = VpT; g.O1 = VmT; g.O2 = VmT;
    g.bX0 = bvp; g.bX1 = bvm; g.bX2 = bvm;
    g.bY0 = nullptr; g.bY1 = nullptr; g.bY2 = nullptr;
    g.K0 = 4096; g.K1 = 4096; g.K2 = 4096; g.M2 = 2048;
    gemm_batch<<<dim3(32, 16, 2), blk, 0, stream>>>(g);
  }

  attn_kernel<<<1024, blk, 0, stream>>>(Qm, Kpm, Kmm, VpT, VmT, pan, ms, (float*)d_out);
}